// Round 8
// baseline (21955.182 us; speedup 1.0000x reference)
//
#include <hip/hip_runtime.h>

typedef __attribute__((ext_vector_type(8))) short short8;
typedef __attribute__((ext_vector_type(4))) float f32x4;
typedef __attribute__((ext_vector_type(4))) unsigned uint32x4;

#define SEQ 4096
#define HID 2048
#define G4  8192
#define NBLK 256

static __device__ __forceinline__ ushort f2bf(float f) {
    unsigned u = __float_as_uint(f);
    u = (u + 0x7fffu + ((u >> 16) & 1u)) >> 16;   // RNE
    return (ushort)u;
}
static __device__ __forceinline__ float bf_lo(unsigned x) { return __uint_as_float(x << 16); }
static __device__ __forceinline__ float bf_hi(unsigned x) { return __uint_as_float(x & 0xffff0000u); }

// 16 B coherent read (sc0 sc1 bypass local caches) + wait.
static __device__ __forceinline__ uint32x4 load_coh_x4(const void* p) {
    unsigned long long ap = (unsigned long long)p;
    uint32x4 v;
    asm volatile("global_load_dwordx4 %0, %1, off sc0 sc1\n\ts_waitcnt vmcnt(0)"
                 : "=&v"(v) : "v"(ap) : "memory");
    return v;
}
// RETURNING f32 atomic swap (sc0 = return old) + vmcnt(0): the returned value
// proves completion at the coherence point -> publishes are ordered before
// anything issued after this.
static __device__ __forceinline__ float atomic_swap_ret_f32(float* p, float v) {
    unsigned long long ap = (unsigned long long)p;
    float old;
    asm volatile("global_atomic_swap %0, %1, %2, off sc0\n\ts_waitcnt vmcnt(0)"
                 : "=&v"(old) : "v"(ap), "v"(v) : "memory");
    return old;
}
// fire-and-forget u32 atomic swap (tag publish)
static __device__ __forceinline__ void atomic_pub_u32(unsigned* p, unsigned v) {
    unsigned long long ap = (unsigned long long)p;
    asm volatile("global_atomic_swap %0, %1, off" :: "v"(ap), "v"(v) : "memory");
}

// h_lds address map: +4 floats pad per 32 floats -> reads <=2-way bank aliased
static __device__ __forceinline__ int hmap(int col) { return col + ((col >> 5) << 2); }

static __device__ __forceinline__ float fsigmoid(float x) {
    return 1.0f / (1.0f + __expf(-x));
}
static __device__ __forceinline__ float ftanh(float x) {
    return 1.0f - 2.0f / (__expf(2.0f * x) + 1.0f);
}

// ---------------- f32 -> bf16 conversion (vectorized, 4 elems/thread) ----------
__global__ void __launch_bounds__(256) k_f32_to_bf16(const float* __restrict__ in,
                                                     ushort* __restrict__ out, int n4) {
    int i = blockIdx.x * blockDim.x + threadIdx.x;
    if (i < n4) {
        float4 v = ((const float4*)in)[i];
        ushort4 o;
        o.x = f2bf(v.x); o.y = f2bf(v.y); o.z = f2bf(v.z); o.w = f2bf(v.w);
        ((ushort4*)out)[i] = o;
    }
}

// ---------------- xg = x @ W_ih^T + (b_ih + b_hh), bf16 MFMA, 128x128 tile ------
__global__ void __launch_bounds__(256) k_gemm_xg(
    const ushort* __restrict__ A, const ushort* __restrict__ B,
    const float* __restrict__ bih, const float* __restrict__ bhh,
    float* __restrict__ C)
{
    __shared__ ushort Asm[128 * 40];
    __shared__ ushort Bsm[128 * 40];
    const int tid = threadIdx.x;
    const int brow = blockIdx.y * 128;
    const int bcol = blockIdx.x * 128;
    const int w = tid >> 6, l = tid & 63;
    const int wm = w >> 1, wn = w & 1;

    f32x4 acc[4][4] = {};

    for (int k0 = 0; k0 < 2048; k0 += 32) {
        __syncthreads();
        #pragma unroll
        for (int i = 0; i < 2; ++i) {
            int q = tid + i * 256;
            int r = q >> 2, kc = q & 3;
            *(uint4*)((char*)Asm + r * 80 + kc * 16) =
                *(const uint4*)(A + (size_t)(brow + r) * 2048 + k0 + kc * 8);
            *(uint4*)((char*)Bsm + r * 80 + kc * 16) =
                *(const uint4*)(B + (size_t)(bcol + r) * 2048 + k0 + kc * 8);
        }
        __syncthreads();

        short8 af[4], bf[4];
        #pragma unroll
        for (int m = 0; m < 4; ++m)
            af[m] = *(const short8*)((char*)Asm + (wm * 64 + m * 16 + (l & 15)) * 80 + (l >> 4) * 16);
        #pragma unroll
        for (int n = 0; n < 4; ++n)
            bf[n] = *(const short8*)((char*)Bsm + (wn * 64 + n * 16 + (l & 15)) * 80 + (l >> 4) * 16);

        #pragma unroll
        for (int m = 0; m < 4; ++m)
            #pragma unroll
            for (int n = 0; n < 4; ++n)
                acc[m][n] = __builtin_amdgcn_mfma_f32_16x16x32_bf16(af[m], bf[n], acc[m][n], 0, 0, 0);
    }

    const int lr = (l >> 4) * 4, lc = l & 15;
    #pragma unroll
    for (int m = 0; m < 4; ++m)
        #pragma unroll
        for (int n = 0; n < 4; ++n) {
            int col = bcol + wn * 64 + n * 16 + lc;
            float bsum = bih[col] + bhh[col];
            #pragma unroll
            for (int r = 0; r < 4; ++r) {
                int rowg = brow + wm * 64 + m * 16 + lr + r;
                C[(size_t)rowg * 8192 + col] = acc[m][n][r] + bsum;
            }
        }
}

// ---------------- persistent cooperative LSTM recurrence ------------------------
// 256 blocks x 512 threads. Wave u owns unit hbase+u for the dot (register-f32
// W slice). Exchange protocol (split tag/data):
//   hpar[2][2048] f32 : parity double-buffered h values (plain f32 slots)
//   tags[256] u32     : tag[b] = latest h index block b has published (monotonic)
// step t: wave1 polls all 256 tags >= t (1 KB sweep) -> barrier -> all threads
// coherent-read h_t from hpar[t&1] ONCE -> dot -> reduce -> barrier -> wave0
// lanes 0-7: gates, c, h -> 8 RETURNING atomic swaps into hpar[(t+1)&1]
// (vmcnt(0) proves L3 completion) -> lane0 publishes tag[b]=t+1.
// Overwrite safety (induction as R6/R7): passing poll >= t implies every block
// published h_t, which happens only after its reads of h_{t-1} completed; so
// writing h_{t+1} over h_{t-1} (same parity) can't race any reader.
// Initial state: tags=0, hpar[0]=0 ( = h_0 published) via host memset.
__global__ void __launch_bounds__(512, 1) k_lstm_rec(
    const ushort* __restrict__ Whh,   // bf16 [8192][2048]
    const float* __restrict__ xg,     // [4096][8192]
    float* __restrict__ hpar,         // [2][2048] f32
    unsigned* __restrict__ tags,      // [256]
    const float* __restrict__ Wlin,   // [2048]
    const float* __restrict__ blin,   // [1]
    float* __restrict__ out)          // [1]
{
    extern __shared__ char smem[];
    float* h_lds = (float*)smem;              // hmap(2044)+4 = 2300 f32 (9216 B)
    float* g_lds = (float*)(smem + 9216);     // 32 gate sums
    float* r_lds = (float*)(smem + 9216 + 128); // 8 f32 final-reduce scratch

    const int tid = threadIdx.x;
    const int b   = blockIdx.x;
    const int hbase = b * 8;
    const int u  = tid >> 6;        // wave id = local hidden unit (dot phase)
    const int g  = (tid >> 4) & 3;  // gate (torch order i,f,g,o)
    const int cc = tid & 15;        // col-chunk

    // one-time: stage + expand this thread's W row slice to f32 registers
    // row = g*2048 + hbase + u, cols cc*8 + k*128 + j (j=0..7, k=0..15)
    f32x4 wf[32];
    {
        const ushort* wr = Whh + (size_t)((g << 11) + hbase + u) * 2048 + (cc << 3);
        #pragma unroll
        for (int k = 0; k < 16; ++k) {
            uint4 wv = *(const uint4*)(wr + (k << 7));
            wf[2 * k]     = (f32x4){bf_lo(wv.x), bf_hi(wv.x), bf_lo(wv.y), bf_hi(wv.y)};
            wf[2 * k + 1] = (f32x4){bf_lo(wv.z), bf_hi(wv.z), bf_lo(wv.w), bf_hi(wv.w)};
        }
    }

    float c_reg = 0.0f;   // live on wave 0 lanes 0-7 (unit = lane)

    for (int t = 0; t < SEQ; ++t) {
        const float* src = hpar + (size_t)(t & 1) * HID;
        float*       dst = hpar + (size_t)((t + 1) & 1) * HID;

        // wave-0 xg prefetch for this step (plain cached loads, issued early)
        float xgv0 = 0.f, xgv1 = 0.f, xgv2 = 0.f, xgv3 = 0.f;
        if (tid < 8) {
            const float* xr = xg + (size_t)t * G4 + hbase + tid;
            xgv0 = xr[0]; xgv1 = xr[2048]; xgv2 = xr[4096]; xgv3 = xr[6144];
        }

        // wave 1 polls the compact tag array (256 u32 = 1 KB per sweep)
        if (u == 1) {
            const unsigned tgt = (unsigned)t;
            const unsigned* tp = tags + (tid & 63) * 4;
            while (true) {
                uint32x4 f = load_coh_x4(tp);
                unsigned m01 = f.x < f.y ? f.x : f.y;
                unsigned m23 = f.z < f.w ? f.z : f.w;
                unsigned m = m01 < m23 ? m01 : m23;
                if (__all(m >= tgt)) break;
                __builtin_amdgcn_s_sleep(1);
            }
        }
        __syncthreads();   // [P] all 256 tags >= t: h_t fully published

        // read h_t ONCE (16 B coherent per thread), stage into padded LDS
        {
            uint32x4 d = load_coh_x4(src + tid * 4);
            *(f32x4*)(h_lds + hmap(tid * 4)) =
                (f32x4){__uint_as_float(d.x), __uint_as_float(d.y),
                        __uint_as_float(d.z), __uint_as_float(d.w)};
        }
        __syncthreads();   // [A] h_t staged

        // dot: pure f32 FMA, W from registers, h from LDS (4 indep chains)
        float s0 = 0.f, s1 = 0.f, s2 = 0.f, s3 = 0.f;
        #pragma unroll
        for (int k = 0; k < 16; ++k) {
            int col0 = (cc << 3) + (k << 7);
            const float* hp = h_lds + hmap(col0);
            f32x4 ha = *(const f32x4*)hp;
            f32x4 hb = *(const f32x4*)(hp + 4);
            f32x4 wa = wf[2 * k], wb = wf[2 * k + 1];
            s0 += wa.x * ha.x;  s1 += wa.y * ha.y;
            s2 += wa.z * ha.z;  s3 += wa.w * ha.w;
            s0 += wb.x * hb.x;  s1 += wb.y * hb.y;
            s2 += wb.z * hb.z;  s3 += wb.w * hb.w;
        }
        float sum = (s0 + s1) + (s2 + s3);
        sum += __shfl_xor(sum, 1);
        sum += __shfl_xor(sum, 2);
        sum += __shfl_xor(sum, 4);
        sum += __shfl_xor(sum, 8);
        if (cc == 0) g_lds[u * 4 + g] = sum;   // W_hh partial only
        __syncthreads();   // [B] all gate sums in g_lds; LDS reads done

        // wave 0 lanes 0-7: gates, state update, coalesced coherent publish
        if (tid < 8) {
            float gi = fsigmoid(g_lds[tid * 4 + 0] + xgv0);
            float gf = fsigmoid(g_lds[tid * 4 + 1] + xgv1);
            float tg = ftanh   (g_lds[tid * 4 + 2] + xgv2);
            float go = fsigmoid(g_lds[tid * 4 + 3] + xgv3);
            c_reg = gf * c_reg + gi * tg;
            float hn = go * ftanh(c_reg);
            // 8 lanes, ONE instruction, returning swap + vmcnt(0) inside:
            float old = atomic_swap_ret_f32(&dst[hbase + tid], hn);
            asm volatile("" :: "v"(old));   // keep the ack live
        }
        if (tid == 0)
            atomic_pub_u32(&tags[b], (unsigned)(t + 1));
        // no extra barrier: next iteration's [P] orders h_lds reuse
    }

    // final: out = sigmoid(h_SEQ . W_lin + b_lin), block 0 only
    if (b == 0) {
        if (u == 1) {
            const unsigned tgt = (unsigned)SEQ;
            const unsigned* tp = tags + (tid & 63) * 4;
            while (true) {
                uint32x4 f = load_coh_x4(tp);
                unsigned m01 = f.x < f.y ? f.x : f.y;
                unsigned m23 = f.z < f.w ? f.z : f.w;
                unsigned m = m01 < m23 ? m01 : m23;
                if (__all(m >= tgt)) break;
                __builtin_amdgcn_s_sleep(1);
            }
        }
        __syncthreads();
        // h_SEQ lives in hpar[SEQ&1] = hpar[0]
        uint32x4 d = load_coh_x4(hpar + tid * 4);
        const float* wl = Wlin + tid * 4;
        float s = __uint_as_float(d.x) * wl[0] + __uint_as_float(d.y) * wl[1]
                + __uint_as_float(d.z) * wl[2] + __uint_as_float(d.w) * wl[3];
        #pragma unroll
        for (int o = 1; o < 64; o <<= 1) s += __shfl_xor(s, o);
        if ((tid & 63) == 0) r_lds[u] = s;
        __syncthreads();
        if (tid == 0) {
            float tot = r_lds[0] + r_lds[1] + r_lds[2] + r_lds[3]
                      + r_lds[4] + r_lds[5] + r_lds[6] + r_lds[7] + blin[0];
            out[0] = fsigmoid(tot);
        }
    }
}

extern "C" void kernel_launch(void* const* d_in, const int* in_sizes, int n_in,
                              void* d_out, int out_size, void* d_ws, size_t ws_size,
                              hipStream_t stream) {
    const float* x    = (const float*)d_in[0];   // [1][4096][2048]
    const float* Wih  = (const float*)d_in[1];   // [8192][2048]
    const float* Whh  = (const float*)d_in[2];   // [8192][2048]
    const float* bih  = (const float*)d_in[3];   // [8192]
    const float* bhh  = (const float*)d_in[4];   // [8192]
    const float* Wlin = (const float*)d_in[5];   // [1][2048]
    const float* blin = (const float*)d_in[6];   // [1]
    float* out = (float*)d_out;

    char* ws = (char*)d_ws;
    float*    xgbuf = (float*)ws;                         // 134,217,728 B
    ushort*   xbf   = (ushort*)(ws + 134217728);          //  16,777,216 B
    ushort*   wihbf = (ushort*)(ws + 150994944);          //  33,554,432 B
    ushort*   whhbf = (ushort*)(ws + 184549376);          //  33,554,432 B
    float*    hpar  = (float*)(ws + 218103808);           //      16,384 B (2x2048 f32)
    unsigned* tags  = (unsigned*)(ws + 218120192);        //       1,024 B

    // f32 -> bf16 (x, W_ih, W_hh)
    k_f32_to_bf16<<<8192,  256, 0, stream>>>(x,   xbf,   2097152);
    k_f32_to_bf16<<<16384, 256, 0, stream>>>(Wih, wihbf, 4194304);
    k_f32_to_bf16<<<16384, 256, 0, stream>>>(Whh, whhbf, 4194304);

    // input GEMM: all timesteps' input-side gate preactivations
    k_gemm_xg<<<dim3(64, 32), 256, 0, stream>>>(xbf, wihbf, bih, bhh, xgbuf);

    // initial state every call: tags=0 and hpar[0]=0  <=>  h_0 published
    hipMemsetAsync(hpar, 0, HID * sizeof(float), stream);
    hipMemsetAsync(tags, 0, NBLK * sizeof(unsigned), stream);

    // persistent cooperative recurrence: proven launch config (dyn LDS + attr)
    hipFuncSetAttribute((const void*)k_lstm_rec,
                        hipFuncAttributeMaxDynamicSharedMemorySize, 163840);
    void* args[] = { (void*)&whhbf, (void*)&xgbuf, (void*)&hpar, (void*)&tags,
                     (void*)&Wlin, (void*)&blin, (void*)&out };
    hipLaunchCooperativeKernel((const void*)k_lstm_rec, dim3(NBLK), dim3(512),
                               args, 139520, stream);
}

// Round 9
// 14906.587 us; speedup vs baseline: 1.4729x; 1.4729x over previous
//
#include <hip/hip_runtime.h>

typedef __attribute__((ext_vector_type(8))) short short8;
typedef __attribute__((ext_vector_type(4))) float f32x4;
typedef __attribute__((ext_vector_type(4))) unsigned uint32x4;

#define SEQ 4096
#define HID 2048
#define G4  8192
#define NBLK 256

static __device__ __forceinline__ ushort f2bf(float f) {
    unsigned u = __float_as_uint(f);
    u = (u + 0x7fffu + ((u >> 16) & 1u)) >> 16;   // RNE
    return (ushort)u;
}
static __device__ __forceinline__ float bf_lo(unsigned x) { return __uint_as_float(x << 16); }
static __device__ __forceinline__ float bf_hi(unsigned x) { return __uint_as_float(x & 0xffff0000u); }

// Fire-and-forget publish of one {f32 h (lo), u32 tag (hi)} u64 at the device
// coherence point. 8 lanes of one wave -> ONE instruction, one 64 B line.
static __device__ __forceinline__ void atomic_pub_u64(unsigned long long* p,
                                                      unsigned long long v) {
    unsigned long long ap = (unsigned long long)p;
    asm volatile("global_atomic_swap_x2 %0, %1, off" :: "v"(ap), "v"(v) : "memory");
}

// 32 B coherent read (two dwordx4, sc0 sc1 bypass local caches), one waitcnt.
static __device__ __forceinline__ void load_slot8(const unsigned long long* p,
                                                  uint32x4& a, uint32x4& b) {
    unsigned long long ap = (unsigned long long)p;
    asm volatile("global_load_dwordx4 %0, %2, off sc0 sc1\n\t"
                 "global_load_dwordx4 %1, %2, off offset:16 sc0 sc1\n\t"
                 "s_waitcnt vmcnt(0)"
                 : "=&v"(a), "=&v"(b) : "v"(ap) : "memory");
}

// h_lds address map: +4 floats pad per 32 floats -> reads <=2-way bank aliased
static __device__ __forceinline__ int hmap(int col) { return col + ((col >> 5) << 2); }

static __device__ __forceinline__ float fsigmoid(float x) {
    return 1.0f / (1.0f + __expf(-x));
}
static __device__ __forceinline__ float ftanh(float x) {
    return 1.0f - 2.0f / (__expf(2.0f * x) + 1.0f);
}

// ---------------- f32 -> bf16 conversion (vectorized, 4 elems/thread) ----------
__global__ void __launch_bounds__(256) k_f32_to_bf16(const float* __restrict__ in,
                                                     ushort* __restrict__ out, int n4) {
    int i = blockIdx.x * blockDim.x + threadIdx.x;
    if (i < n4) {
        float4 v = ((const float4*)in)[i];
        ushort4 o;
        o.x = f2bf(v.x); o.y = f2bf(v.y); o.z = f2bf(v.z); o.w = f2bf(v.w);
        ((ushort4*)out)[i] = o;
    }
}

// ---------------- xg = x @ W_ih^T + (b_ih + b_hh), bf16 MFMA, 128x128 tile ------
__global__ void __launch_bounds__(256) k_gemm_xg(
    const ushort* __restrict__ A, const ushort* __restrict__ B,
    const float* __restrict__ bih, const float* __restrict__ bhh,
    float* __restrict__ C)
{
    __shared__ ushort Asm[128 * 40];
    __shared__ ushort Bsm[128 * 40];
    const int tid = threadIdx.x;
    const int brow = blockIdx.y * 128;
    const int bcol = blockIdx.x * 128;
    const int w = tid >> 6, l = tid & 63;
    const int wm = w >> 1, wn = w & 1;

    f32x4 acc[4][4] = {};

    for (int k0 = 0; k0 < 2048; k0 += 32) {
        __syncthreads();
        #pragma unroll
        for (int i = 0; i < 2; ++i) {
            int q = tid + i * 256;
            int r = q >> 2, kc = q & 3;
            *(uint4*)((char*)Asm + r * 80 + kc * 16) =
                *(const uint4*)(A + (size_t)(brow + r) * 2048 + k0 + kc * 8);
            *(uint4*)((char*)Bsm + r * 80 + kc * 16) =
                *(const uint4*)(B + (size_t)(bcol + r) * 2048 + k0 + kc * 8);
        }
        __syncthreads();

        short8 af[4], bf[4];
        #pragma unroll
        for (int m = 0; m < 4; ++m)
            af[m] = *(const short8*)((char*)Asm + (wm * 64 + m * 16 + (l & 15)) * 80 + (l >> 4) * 16);
        #pragma unroll
        for (int n = 0; n < 4; ++n)
            bf[n] = *(const short8*)((char*)Bsm + (wn * 64 + n * 16 + (l & 15)) * 80 + (l >> 4) * 16);

        #pragma unroll
        for (int m = 0; m < 4; ++m)
            #pragma unroll
            for (int n = 0; n < 4; ++n)
                acc[m][n] = __builtin_amdgcn_mfma_f32_16x16x32_bf16(af[m], bf[n], acc[m][n], 0, 0, 0);
    }

    const int lr = (l >> 4) * 4, lc = l & 15;
    #pragma unroll
    for (int m = 0; m < 4; ++m)
        #pragma unroll
        for (int n = 0; n < 4; ++n) {
            int col = bcol + wn * 64 + n * 16 + lc;
            float bsum = bih[col] + bhh[col];
            #pragma unroll
            for (int r = 0; r < 4; ++r) {
                int rowg = brow + wm * 64 + m * 16 + lr + r;
                C[(size_t)rowg * 8192 + col] = acc[m][n][r] + bsum;
            }
        }
}

// ---------------- persistent cooperative LSTM recurrence ------------------------
// Merged best-of (R5 protocol + R7 dbuf/compute + R8 tail):
//  - hslot[2][2048] u64 {f32 h, u32 tag}, PARITY double-buffered; consumer at
//    step t polls buf[t&1] for tag==t (deadlock/race-free by the R7 induction:
//    overwriting buf[p] needs every block past step t+1's poll, which needs
//    all reads of buf[p]@t complete).
//  - poll: each thread its OWN 4 slots (distinct lines; data travels with tag;
//    one 32B coherent read per iteration).
//  - dot: W_hh slice pre-expanded f32 in registers, wave u owns unit hbase+u,
//    lane=(gate g, col-chunk cc); pure-FMA, shuffle reduce, g_lds[u*4+g].
//  - tail: wave 0 lanes 0-7 do gates + c update, then publish all 8 units in
//    ONE fire-and-forget swap_x2 (coalesced 64 B line).
__global__ void __launch_bounds__(512, 1) k_lstm_rec(
    const ushort* __restrict__ Whh,          // bf16 [8192][2048]
    const float* __restrict__ xg,            // [4096][8192]
    unsigned long long* __restrict__ hslot,  // [2][2048] {h,tag}, 0xFF-memset
    const float* __restrict__ Wlin,          // [2048]
    const float* __restrict__ blin,          // [1]
    float* __restrict__ out)                 // [1]
{
    extern __shared__ char smem[];
    float* h_lds = (float*)smem;                // 2304 f32 padded (9216 B)
    float* g_lds = (float*)(smem + 9216);       // 32 gate sums
    float* r_lds = (float*)(smem + 9216 + 128); // 8 f32 final-reduce scratch

    const int tid = threadIdx.x;
    const int b   = blockIdx.x;
    const int hbase = b * 8;
    const int u  = tid >> 6;        // wave id = local hidden unit
    const int g  = (tid >> 4) & 3;  // gate (torch order i,f,g,o)
    const int cc = tid & 15;        // col-chunk

    // one-time: stage + expand this thread's W row slice to f32 registers
    // row = g*2048 + hbase + u, cols cc*8 + k*128 + j (j=0..7, k=0..15)
    f32x4 wf[32];
    {
        const ushort* wr = Whh + (size_t)((g << 11) + hbase + u) * 2048 + (cc << 3);
        #pragma unroll
        for (int k = 0; k < 16; ++k) {
            uint4 wv = *(const uint4*)(wr + (k << 7));
            wf[2 * k]     = (f32x4){bf_lo(wv.x), bf_hi(wv.x), bf_lo(wv.y), bf_hi(wv.y)};
            wf[2 * k + 1] = (f32x4){bf_lo(wv.z), bf_hi(wv.z), bf_lo(wv.w), bf_hi(wv.w)};
        }
    }

    float c_reg = 0.0f;   // lives on wave 0 lanes 0-7 (unit = lane)

    // publish h_0 = 0 with tag 0 into buf[0] (one coalesced wave-instruction)
    if (tid < 8)
        atomic_pub_u64(&hslot[hbase + tid], 0ull);

    for (int t = 0; t < SEQ; ++t) {
        const unsigned long long* src = hslot + (size_t)(t & 1) * HID;
        unsigned long long*       dst = hslot + (size_t)((t + 1) & 1) * HID;

        // wave-0 xg prefetch (independent of h; plain cached loads)
        float xgv0 = 0.f, xgv1 = 0.f, xgv2 = 0.f, xgv3 = 0.f;
        if (tid < 8) {
            const float* xr = xg + (size_t)t * G4 + hbase + tid;
            xgv0 = xr[0]; xgv1 = xr[2048]; xgv2 = xr[4096]; xgv3 = xr[6144];
        }

        // poll own 4 slots of buf[t&1] until tags == t; stage h into LDS
        {
            const unsigned tgt = (unsigned)t;
            uint32x4 a, bq;
            int spin = 0;
            while (true) {
                load_slot8(src + tid * 4, a, bq);
                if (a.y == tgt && a.w == tgt && bq.y == tgt && bq.w == tgt) break;
                if ((++spin & 63) == 0) {
                    // escape hatch (R5-proven): acquire emits inv in the
                    // (never-observed) case sc0sc1 loads return stale data
                    unsigned d = __hip_atomic_load((const unsigned*)src,
                                                   __ATOMIC_ACQUIRE, __HIP_MEMORY_SCOPE_AGENT);
                    asm volatile("" :: "v"(d));
                } else {
                    __builtin_amdgcn_s_sleep(1);
                }
            }
            *(f32x4*)(h_lds + hmap(tid * 4)) =
                (f32x4){__uint_as_float(a.x), __uint_as_float(a.z),
                        __uint_as_float(bq.x), __uint_as_float(bq.z)};
        }
        __syncthreads();   // [A] h_t staged; all reads of buf[t&1] complete

        // dot: pure f32 FMA, W from registers, h from LDS (4 indep chains)
        float s0 = 0.f, s1 = 0.f, s2 = 0.f, s3 = 0.f;
        #pragma unroll
        for (int k = 0; k < 16; ++k) {
            int col0 = (cc << 3) + (k << 7);
            const float* hp = h_lds + hmap(col0);
            f32x4 ha = *(const f32x4*)hp;
            f32x4 hb = *(const f32x4*)(hp + 4);
            f32x4 wa = wf[2 * k], wb = wf[2 * k + 1];
            s0 += wa.x * ha.x;  s1 += wa.y * ha.y;
            s2 += wa.z * ha.z;  s3 += wa.w * ha.w;
            s0 += wb.x * hb.x;  s1 += wb.y * hb.y;
            s2 += wb.z * hb.z;  s3 += wb.w * hb.w;
        }
        float sum = (s0 + s1) + (s2 + s3);
        // reduce over the 16 cc lanes (intra-wave)
        sum += __shfl_xor(sum, 1);
        sum += __shfl_xor(sum, 2);
        sum += __shfl_xor(sum, 4);
        sum += __shfl_xor(sum, 8);
        if (cc == 0) g_lds[u * 4 + g] = sum;   // W_hh partial (xg added in tail)
        __syncthreads();   // [B] all 32 gate sums visible; LDS reads done

        // wave 0 lanes 0-7: gates, state update, ONE coalesced publish
        if (tid < 8) {
            float gi = fsigmoid(g_lds[tid * 4 + 0] + xgv0);
            float gf = fsigmoid(g_lds[tid * 4 + 1] + xgv1);
            float tg = ftanh   (g_lds[tid * 4 + 2] + xgv2);
            float go = fsigmoid(g_lds[tid * 4 + 3] + xgv3);
            c_reg = gf * c_reg + gi * tg;
            float hn = go * ftanh(c_reg);
            unsigned long long pv =
                ((unsigned long long)(unsigned)(t + 1) << 32) |
                (unsigned long long)__float_as_uint(hn);
            atomic_pub_u64(&dst[hbase + tid], pv);
        }
        // no trailing barrier: next-iter poll gates all h_lds/g_lds reuse
        // (tags t+1 appear only after wave0's g_lds reads completed)
    }

    // final: out = sigmoid(h_SEQ . W_lin + b_lin), block 0 only
    // h_SEQ carries tag SEQ in buf[SEQ&1] = buf[0]
    if (b == 0) {
        const unsigned tgt = (unsigned)SEQ;
        uint32x4 a, bq;
        int spin = 0;
        while (true) {
            load_slot8(hslot + tid * 4, a, bq);
            if (a.y == tgt && a.w == tgt && bq.y == tgt && bq.w == tgt) break;
            if ((++spin & 63) == 0) {
                unsigned d = __hip_atomic_load((const unsigned*)hslot,
                                               __ATOMIC_ACQUIRE, __HIP_MEMORY_SCOPE_AGENT);
                asm volatile("" :: "v"(d));
            } else {
                __builtin_amdgcn_s_sleep(1);
            }
        }
        const float* wl = Wlin + tid * 4;
        float s = __uint_as_float(a.x)  * wl[0] + __uint_as_float(a.z)  * wl[1]
                + __uint_as_float(bq.x) * wl[2] + __uint_as_float(bq.z) * wl[3];
        #pragma unroll
        for (int o = 1; o < 64; o <<= 1) s += __shfl_xor(s, o);
        if ((tid & 63) == 0) r_lds[u] = s;
        __syncthreads();
        if (tid == 0) {
            float tot = r_lds[0] + r_lds[1] + r_lds[2] + r_lds[3]
                      + r_lds[4] + r_lds[5] + r_lds[6] + r_lds[7] + blin[0];
            out[0] = fsigmoid(tot);
        }
    }
}

extern "C" void kernel_launch(void* const* d_in, const int* in_sizes, int n_in,
                              void* d_out, int out_size, void* d_ws, size_t ws_size,
                              hipStream_t stream) {
    const float* x    = (const float*)d_in[0];   // [1][4096][2048]
    const float* Wih  = (const float*)d_in[1];   // [8192][2048]
    const float* Whh  = (const float*)d_in[2];   // [8192][2048]
    const float* bih  = (const float*)d_in[3];   // [8192]
    const float* bhh  = (const float*)d_in[4];   // [8192]
    const float* Wlin = (const float*)d_in[5];   // [1][2048]
    const float* blin = (const float*)d_in[6];   // [1]
    float* out = (float*)d_out;

    char* ws = (char*)d_ws;
    float*              xgbuf = (float*)ws;                        // 134,217,728 B
    ushort*             xbf   = (ushort*)(ws + 134217728);         //  16,777,216 B
    ushort*             wihbf = (ushort*)(ws + 150994944);         //  33,554,432 B
    ushort*             whhbf = (ushort*)(ws + 184549376);         //  33,554,432 B
    unsigned long long* hslot = (unsigned long long*)(ws + 218103808); // 32,768 B

    // f32 -> bf16 (x, W_ih, W_hh)
    k_f32_to_bf16<<<8192,  256, 0, stream>>>(x,   xbf,   2097152);
    k_f32_to_bf16<<<16384, 256, 0, stream>>>(Wih, wihbf, 4194304);
    k_f32_to_bf16<<<16384, 256, 0, stream>>>(Whh, whhbf, 4194304);

    // input GEMM: all timesteps' input-side gate preactivations
    k_gemm_xg<<<dim3(64, 32), 256, 0, stream>>>(xbf, wihbf, bih, bhh, xgbuf);

    // invalidate BOTH parity buffers every call (tags 0..SEQ never match 0xFF)
    hipMemsetAsync(hslot, 0xFF, 2 * HID * sizeof(unsigned long long), stream);

    // persistent cooperative recurrence: proven launch config (dyn LDS + attr)
    hipFuncSetAttribute((const void*)k_lstm_rec,
                        hipFuncAttributeMaxDynamicSharedMemorySize, 163840);
    void* args[] = { (void*)&whhbf, (void*)&xgbuf, (void*)&hslot,
                     (void*)&Wlin, (void*)&blin, (void*)&out };
    hipLaunchCooperativeKernel((const void*)k_lstm_rec, dim3(NBLK), dim3(512),
                               args, 139520, stream);
}